// Round 8
// baseline (152.482 us; speedup 1.0000x reference)
//
#include <hip/hip_runtime.h>
#include <hip/hip_bf16.h>

// Row-wise cosine hinge loss.
//   j = (i + 1 + neg_idx[i]) % B
//   hinge_i = relu(1 - cos(t_i, o_i) + cos(t_j, o_i))
//   out = sum_i hinge_i / B
//
// R8: max-occupancy probe. Every structure so far (reg-buffered, LDS-DMA)
// plateaus at ~4.2 TB/s demand regardless of per-wave MLP -> test the
// per-WAVE outstanding-cap hypothesis by doubling waves/CU to 32 with a
// clean VALU-only (DPP) reduce and <=64 VGPRs, plus prefetching the next
// row's gather index one iteration ahead (removes ~600-cyc dependent
// index fetch from the per-row chain).

#define EPS 1e-6f

typedef float f4 __attribute__((ext_vector_type(4)));

// VALU-pipe wave reduction via DPP; lane 63 holds the 64-lane sum.
#define DPP_STEP(x, ctrl, rm, bm)                                             \
    x += __int_as_float(__builtin_amdgcn_update_dpp(                          \
        0, __float_as_int(x), (ctrl), (rm), (bm), true))

__device__ __forceinline__ float dpp_wave_sum(float x) {
    DPP_STEP(x, 0x111, 0xf, 0xf);  // row_shr:1
    DPP_STEP(x, 0x112, 0xf, 0xf);  // row_shr:2
    DPP_STEP(x, 0x114, 0xf, 0xe);  // row_shr:4
    DPP_STEP(x, 0x118, 0xf, 0xc);  // row_shr:8
    DPP_STEP(x, 0x142, 0xa, 0xf);  // row_bcast:15
    DPP_STEP(x, 0x143, 0xc, 0xf);  // row_bcast:31
    return x;                      // valid in lane 63
}

__global__ __launch_bounds__(256, 8) void hinge_cos_kernel(
    const float* __restrict__ outm,   // [B, D]
    const float* __restrict__ tgt,    // [B, D]
    const int*   __restrict__ negidx, // [B]
    float* __restrict__ res,          // [1] scalar (pre-zeroed)
    int B, int D, float invB) {

    const int lane  = threadIdx.x & 63;
    const int wave  = threadIdx.x >> 6;
    const int gwave = blockIdx.x * 4 + wave;
    const int nwav  = gridDim.x * 4;             // 8192

    float acc = 0.f;                             // per-wave hinge sum (lane 63)

    int i = gwave;
    int jcur = 0;
    if (i < B) {
        jcur = i + 1 + negidx[i];
        if (jcur >= B) jcur -= B;
    }

    while (i < B) {
        const int inext = i + nwav;

        // Prefetch next row's gather index immediately (independent load,
        // resolves while this row's bulk loads are in flight).
        int jn_raw = 0;
        if (inext < B) jn_raw = negidx[inext];

        const f4* o4 = (const f4*)(outm + (size_t)i * D);
        const f4* t4 = (const f4*)(tgt  + (size_t)i * D);
        const f4* n4 = (const f4*)(tgt  + (size_t)jcur * D);

        // 12 independent 16B loads (48 data VGPRs), all issued up front.
        f4 o[4], t[4], n[4];
#pragma unroll
        for (int k = 0; k < 4; ++k)
            o[k] = __builtin_nontemporal_load(&o4[lane + 64 * k]);
#pragma unroll
        for (int k = 0; k < 4; ++k) t[k] = t4[lane + 64 * k];
#pragma unroll
        for (int k = 0; k < 4; ++k) n[k] = n4[lane + 64 * k];

        // Resolve next row's j while loads fly.
        int jnext = inext + 1 + jn_raw;
        if (jnext >= B) jnext -= B;

        float dto = 0.f, dno = 0.f, oo = 0.f, tt = 0.f, nn = 0.f;
#pragma unroll
        for (int k = 0; k < 4; ++k) {
            dto += o[k].x*t[k].x + o[k].y*t[k].y + o[k].z*t[k].z + o[k].w*t[k].w;
            dno += o[k].x*n[k].x + o[k].y*n[k].y + o[k].z*n[k].z + o[k].w*n[k].w;
            oo  += o[k].x*o[k].x + o[k].y*o[k].y + o[k].z*o[k].z + o[k].w*o[k].w;
            tt  += t[k].x*t[k].x + t[k].y*t[k].y + t[k].z*t[k].z + t[k].w*t[k].w;
            nn  += n[k].x*n[k].x + n[k].y*n[k].y + n[k].z*n[k].z + n[k].w*n[k].w;
        }

        dto = dpp_wave_sum(dto);
        dno = dpp_wave_sum(dno);
        oo  = dpp_wave_sum(oo);
        tt  = dpp_wave_sum(tt);
        nn  = dpp_wave_sum(nn);

        if (lane == 63) {
            float no = sqrtf(oo);
            float h  = 1.f - dto / fmaxf(sqrtf(tt) * no, EPS)
                           + dno / fmaxf(sqrtf(nn) * no, EPS);
            acc += fmaxf(h, 0.f);
        }

        jcur = jnext;
        i = inext;
    }

    // Block-level: lane 63 of each wave holds its partial; one atomic/block.
    __shared__ float red[4];
    if (lane == 63) red[wave] = acc;
    __syncthreads();
    if (threadIdx.x == 0) {
        float s = 0.f;
#pragma unroll
        for (int w = 0; w < 4; ++w) s += red[w];
        atomicAdd(res, s * invB);
    }
}

extern "C" void kernel_launch(void* const* d_in, const int* in_sizes, int n_in,
                              void* d_out, int out_size, void* d_ws, size_t ws_size,
                              hipStream_t stream) {
    const float* outm   = (const float*)d_in[0];
    const float* tgt    = (const float*)d_in[1];
    const int*   negidx = (const int*)d_in[2];
    float* res = (float*)d_out;

    const int B = in_sizes[2];
    const int D = in_sizes[0] / B;

    (void)hipMemsetAsync(res, 0, sizeof(float), stream);

    // 2048 blocks x 256 thr = 8192 waves = 32 waves/CU (8/SIMD at <=64 VGPR);
    // each wave handles 2 rows with the index prefetched one row ahead.
    hinge_cos_kernel<<<2048, 256, 0, stream>>>(outm, tgt, negidx, res, B, D,
                                               1.0f / (float)B);
}

// Round 9
// 146.542 us; speedup vs baseline: 1.0405x; 1.0405x over previous
//
#include <hip/hip_runtime.h>
#include <hip/hip_bf16.h>

// Row-wise cosine hinge loss.
//   j = (i + 1 + neg_idx[i]) % B
//   hinge_i = relu(1 - cos(t_i, o_i) + cos(t_j, o_i))
//   out = sum_i hinge_i / B
//
// R9: fully-unrolled ping-pong register pipeline. Evidence R4/R5/R8: any
// intra-iteration load->consume sequence gets collapsed by the compiler
// into a ~4-register vmcnt convoy (VGPR_Count pinned at 32-48). R6 (cross-
// iteration double buffer) was the only structure to break 40 us. Here:
// exactly 4 rows/wave (B=16384, 4096 waves), buffers A/B alternate with no
// copies, all 4 gather indices scalar-loaded up front, sched_barrier(0)
// fences force "issue next 12 loads BEFORE consuming current" so every
// consume waits at vmcnt(12), never vmcnt(0).

#define EPS 1e-6f

typedef float f4 __attribute__((ext_vector_type(4)));

// VALU-pipe wave reduction via DPP; lane 63 holds the 64-lane sum.
#define DPP_STEP(x, ctrl, rm, bm)                                             \
    x += __int_as_float(__builtin_amdgcn_update_dpp(                          \
        0, __float_as_int(x), (ctrl), (rm), (bm), true))

__device__ __forceinline__ float dpp_wave_sum(float x) {
    DPP_STEP(x, 0x111, 0xf, 0xf);  // row_shr:1
    DPP_STEP(x, 0x112, 0xf, 0xf);  // row_shr:2
    DPP_STEP(x, 0x114, 0xf, 0xe);  // row_shr:4
    DPP_STEP(x, 0x118, 0xf, 0xc);  // row_shr:8
    DPP_STEP(x, 0x142, 0xa, 0xf);  // row_bcast:15
    DPP_STEP(x, 0x143, 0xc, 0xf);  // row_bcast:31
    return x;                      // valid in lane 63
}

struct Buf { f4 o[4], t[4], n[4]; };

__device__ __forceinline__ void issue(Buf& b,
                                      const float* __restrict__ ob,
                                      const float* __restrict__ tb,
                                      const float* __restrict__ nb,
                                      int lane) {
#pragma unroll
    for (int k = 0; k < 4; ++k)
        b.o[k] = __builtin_nontemporal_load((const f4*)ob + lane + 64 * k);
#pragma unroll
    for (int k = 0; k < 4; ++k) b.t[k] = *((const f4*)tb + lane + 64 * k);
#pragma unroll
    for (int k = 0; k < 4; ++k) b.n[k] = *((const f4*)nb + lane + 64 * k);
}

// Hinge for one row; valid in lane 63 (other lanes hold garbage, never read).
__device__ __forceinline__ float consume(const Buf& b) {
    float dto = 0.f, dno = 0.f, oo = 0.f, tt = 0.f, nn = 0.f;
#pragma unroll
    for (int k = 0; k < 4; ++k) {
        dto += b.o[k].x*b.t[k].x + b.o[k].y*b.t[k].y + b.o[k].z*b.t[k].z + b.o[k].w*b.t[k].w;
        dno += b.o[k].x*b.n[k].x + b.o[k].y*b.n[k].y + b.o[k].z*b.n[k].z + b.o[k].w*b.n[k].w;
        oo  += b.o[k].x*b.o[k].x + b.o[k].y*b.o[k].y + b.o[k].z*b.o[k].z + b.o[k].w*b.o[k].w;
        tt  += b.t[k].x*b.t[k].x + b.t[k].y*b.t[k].y + b.t[k].z*b.t[k].z + b.t[k].w*b.t[k].w;
        nn  += b.n[k].x*b.n[k].x + b.n[k].y*b.n[k].y + b.n[k].z*b.n[k].z + b.n[k].w*b.n[k].w;
    }
    dto = dpp_wave_sum(dto);
    dno = dpp_wave_sum(dno);
    oo  = dpp_wave_sum(oo);
    tt  = dpp_wave_sum(tt);
    nn  = dpp_wave_sum(nn);
    float no = sqrtf(oo);
    float h  = 1.f - dto / fmaxf(sqrtf(tt) * no, EPS)
                   + dno / fmaxf(sqrtf(nn) * no, EPS);
    return fmaxf(h, 0.f);
}

// Specialized: exactly 4 rows per wave (requires B == 16 * gridDim.x).
__global__ __launch_bounds__(256, 4) void hinge_cos_pipe4(
    const float* __restrict__ outm, const float* __restrict__ tgt,
    const int* __restrict__ negidx, float* __restrict__ res,
    int B, int D, float invB) {

    const int lane  = threadIdx.x & 63;
    const int wave  = threadIdx.x >> 6;
    const int gwave = blockIdx.x * 4 + wave;
    const int nw    = gridDim.x * 4;

    const int r0 = gwave, r1 = gwave + nw, r2 = gwave + 2 * nw, r3 = gwave + 3 * nw;
    // Wave-uniform gather indices -> scalar loads, all issued up front.
    int j0 = r0 + 1 + negidx[r0]; if (j0 >= B) j0 -= B;
    int j1 = r1 + 1 + negidx[r1]; if (j1 >= B) j1 -= B;
    int j2 = r2 + 1 + negidx[r2]; if (j2 >= B) j2 -= B;
    int j3 = r3 + 1 + negidx[r3]; if (j3 >= B) j3 -= B;

    Buf A, Bb;
    issue(A,  outm + (size_t)r0 * D, tgt + (size_t)r0 * D, tgt + (size_t)j0 * D, lane);
    issue(Bb, outm + (size_t)r1 * D, tgt + (size_t)r1 * D, tgt + (size_t)j1 * D, lane);
    __builtin_amdgcn_sched_barrier(0);
    float acc = consume(A);                       // waits vmcnt(12)
    issue(A,  outm + (size_t)r2 * D, tgt + (size_t)r2 * D, tgt + (size_t)j2 * D, lane);
    __builtin_amdgcn_sched_barrier(0);
    acc += consume(Bb);                           // waits vmcnt(12)
    issue(Bb, outm + (size_t)r3 * D, tgt + (size_t)r3 * D, tgt + (size_t)j3 * D, lane);
    __builtin_amdgcn_sched_barrier(0);
    acc += consume(A);                            // waits vmcnt(12)
    acc += consume(Bb);

    __shared__ float red[4];
    if (lane == 63) red[wave] = acc;
    __syncthreads();
    if (threadIdx.x == 0) {
        float s = red[0] + red[1] + red[2] + red[3];
        atomicAdd(res, s * invB);
    }
}

// Generic fallback (R8 structure) for shapes not divisible by 16.
__global__ __launch_bounds__(256, 8) void hinge_cos_generic(
    const float* __restrict__ outm, const float* __restrict__ tgt,
    const int* __restrict__ negidx, float* __restrict__ res,
    int B, int D, float invB) {

    const int lane  = threadIdx.x & 63;
    const int wave  = threadIdx.x >> 6;
    const int gwave = blockIdx.x * 4 + wave;
    const int nwav  = gridDim.x * 4;

    float acc = 0.f;
    for (int i = gwave; i < B; i += nwav) {
        int j = i + 1 + negidx[i];
        if (j >= B) j -= B;
        Buf b;
        issue(b, outm + (size_t)i * D, tgt + (size_t)i * D, tgt + (size_t)j * D, lane);
        acc += consume(b);
    }
    __shared__ float red[4];
    if (lane == 63) red[wave] = acc;
    __syncthreads();
    if (threadIdx.x == 0) {
        float s = red[0] + red[1] + red[2] + red[3];
        atomicAdd(res, s * invB);
    }
}

extern "C" void kernel_launch(void* const* d_in, const int* in_sizes, int n_in,
                              void* d_out, int out_size, void* d_ws, size_t ws_size,
                              hipStream_t stream) {
    const float* outm   = (const float*)d_in[0];
    const float* tgt    = (const float*)d_in[1];
    const int*   negidx = (const int*)d_in[2];
    float* res = (float*)d_out;

    const int B = in_sizes[2];
    const int D = in_sizes[0] / B;

    (void)hipMemsetAsync(res, 0, sizeof(float), stream);

    if (D == 1024 && (B % 16) == 0) {
        // B/16 blocks x 4 waves = B/4 waves, exactly 4 rows each, ping-pong
        // pipelined so a consume always has the next row's 12 loads in flight.
        hinge_cos_pipe4<<<B / 16, 256, 0, stream>>>(outm, tgt, negidx, res,
                                                    B, D, 1.0f / (float)B);
    } else {
        hinge_cos_generic<<<2048, 256, 0, stream>>>(outm, tgt, negidx, res,
                                                    B, D, 1.0f / (float)B);
    }
}